// Round 9
// baseline (298.684 us; speedup 1.0000x reference)
//
#include <hip/hip_runtime.h>

#define H 512
#define W 512
#define HW (H * W)
#define BATCH 32
#define KS 5
#define NROWS 4     // rows walked per block (4 -> 2048 blocks, 8/CU, 4 waves/SIMD)
#define NB 2        // batches per thread (K reused in-register across both)

typedef float nf4 __attribute__((ext_vector_type(4)));

// Load one 12-float padded window row (cols w0-4..w0+7) as 3 float4s.
// OOB rows/cols produce zeros. gr is block-uniform (branch, not divergence).
__device__ __forceinline__ void load_row(const float* __restrict__ fb, int gr,
                                         bool wl, bool wr, int w0, nf4* d) {
    if (gr >= 0 && gr < H) {
        const float* row = fb + (size_t)gr * W;
        d[0] = wl ? *reinterpret_cast<const nf4*>(row + w0 - 4) : (nf4)0.f;
        d[1] =      *reinterpret_cast<const nf4*>(row + w0);
        d[2] = wr ? *reinterpret_cast<const nf4*>(row + w0 + 4) : (nf4)0.f;
    } else {
        d[0] = (nf4)0.f; d[1] = (nf4)0.f; d[2] = (nf4)0.f;
    }
}

// NO LDS, NO BARRIERS. 128 threads/block; thread = 4 cols x 2 batches,
// walking 4 rows with a register-rolling 5-row x 12-col f window per batch.
// K tap-rows double-buffered one i-iteration ahead; f row prefetched a full
// step ahead. Latency hiding comes from 4 waves/SIMD (16 waves/CU) — R7's
// identical structure at 2 waves/SIMD sat 80% stalled.
__global__ __launch_bounds__(128, 4) void op2d_kernel(
    const float* __restrict__ f,   // (B,H,W)
    const float* __restrict__ K,   // (5,5,H,W)
    const float* __restrict__ dt,  // (B,)
    float* __restrict__ out)       // (B,H,W)
{
    const int tid  = threadIdx.x;            // 0..127
    const int w0   = tid * 4;                // 0..508
    const int hblk = blockIdx.x * NROWS;     // first output row
    const int b0   = blockIdx.y * NB;        // first batch

    const bool wl = (w0 >= 4);
    const bool wr = (w0 <= 504);

    const float* fb[NB] = { f + (size_t)b0 * HW, f + (size_t)(b0 + 1) * HW };
    const float dtb[NB] = { dt[b0], dt[b0 + 1] };

    // f window: win[b][slot][0..2], slot = (global_row - hblk + 2) mod 5.
    nf4 win[NB][5][3];

    // ---- prologue: rows hblk-2 .. hblk+2 -> slots 0..4 ----
#pragma unroll
    for (int rr = 0; rr < 5; ++rr) {
#pragma unroll
        for (int b = 0; b < NB; ++b)
            load_row(fb[b], hblk - 2 + rr, wl, wr, w0, win[b][rr]);
    }

    // K tap-row 0 of step 0 (in flight alongside the prologue f loads).
    nf4 Kv[2][KS];
#pragma unroll
    for (int j = 0; j < KS; ++j)
        Kv[0][j] = *reinterpret_cast<const nf4*>(
            K + ((size_t)j * H + hblk) * W + w0);

#pragma unroll
    for (int s = 0; s < NROWS; ++s) {
        const int r = hblk + s;              // output row this step

        // Prefetch f row r+3 (enters window slot s%5 at step end; first
        // consumed at step s+1 -> ~a full step of latency cover).
        nf4 nxt[NB][3];
#pragma unroll
        for (int b = 0; b < NB; ++b)
            load_row(fb[b], r + 3, wl, wr, w0, nxt[b]);

        float acc[NB][4] = {{0.f,0.f,0.f,0.f},{0.f,0.f,0.f,0.f}};
        float fc[NB][4];

#pragma unroll
        for (int i = 0; i < KS; ++i) {
            const int g = s * KS + i;        // global tap counter (parity)
            // Prefetch next K tap-row (same step, or row 0 of next step).
            if (i + 1 < KS) {
#pragma unroll
                for (int j = 0; j < KS; ++j)
                    Kv[(g + 1) & 1][j] = *reinterpret_cast<const nf4*>(
                        K + ((size_t)((i + 1) * KS + j) * H + r) * W + w0);
            } else if (s + 1 < NROWS) {
#pragma unroll
                for (int j = 0; j < KS; ++j)
                    Kv[(g + 1) & 1][j] = *reinterpret_cast<const nf4*>(
                        K + ((size_t)j * H + (r + 1)) * W + w0);
            }
            const nf4* Kc = Kv[g & 1];

#pragma unroll
            for (int b = 0; b < NB; ++b) {
                const int slot = (s + i) % 5;          // row r+i-2
                const nf4 ra = win[b][slot][0];
                const nf4 rb = win[b][slot][1];
                const nf4 rc = win[b][slot][2];
                const float buf[12] = { ra.x, ra.y, ra.z, ra.w,
                                        rb.x, rb.y, rb.z, rb.w,
                                        rc.x, rc.y, rc.z, rc.w };
                if (i == 2) { fc[b][0] = rb.x; fc[b][1] = rb.y;
                              fc[b][2] = rb.z; fc[b][3] = rb.w; }
#pragma unroll
                for (int j = 0; j < KS; ++j) {
                    acc[b][0] += Kc[j].x * buf[j + 2];
                    acc[b][1] += Kc[j].y * buf[j + 3];
                    acc[b][2] += Kc[j].z * buf[j + 4];
                    acc[b][3] += Kc[j].w * buf[j + 5];
                }
            }
        }

        // Store both batches' outputs for row r.
#pragma unroll
        for (int b = 0; b < NB; ++b) {
            nf4 o;
            o.x = fmaxf(fc[b][0] + acc[b][0] * dtb[b], 0.f);
            o.y = fmaxf(fc[b][1] + acc[b][1] * dtb[b], 0.f);
            o.z = fmaxf(fc[b][2] + acc[b][2] * dtb[b], 0.f);
            o.w = fmaxf(fc[b][3] + acc[b][3] * dtb[b], 0.f);
            __builtin_nontemporal_store(o,
                reinterpret_cast<nf4*>(out + ((size_t)(b0 + b) * H + r) * W + w0));
        }

        // Rotate: new bottom row (r+3) replaces departing row (r-2), slot s%5.
#pragma unroll
        for (int b = 0; b < NB; ++b) {
            win[b][s % 5][0] = nxt[b][0];
            win[b][s % 5][1] = nxt[b][1];
            win[b][s % 5][2] = nxt[b][2];
        }
    }
}

extern "C" void kernel_launch(void* const* d_in, const int* in_sizes, int n_in,
                              void* d_out, int out_size, void* d_ws, size_t ws_size,
                              hipStream_t stream) {
    const float* f  = (const float*)d_in[0];   // (32,512,512)
    const float* K  = (const float*)d_in[1];   // (5,5,512,512)
    const float* dt = (const float*)d_in[2];   // (32,)
    float* out = (float*)d_out;

    dim3 block(128);
    // x = row-group (128), y = batch-pair (16): 2048 blocks, 8/CU, all
    // co-resident; same-K blocks are 128 IDs apart = 0 mod 8 -> same XCD.
    dim3 grid(H / NROWS, BATCH / NB);
    op2d_kernel<<<grid, block, 0, stream>>>(f, K, dt, out);
}

// Round 10
// 124.020 us; speedup vs baseline: 2.4084x; 2.4084x over previous
//
#include <hip/hip_runtime.h>

#define H 512
#define W 512
#define HW (H * W)
#define BATCH 32
#define KS 5
#define NROWS 4     // rows walked per block -> 2048 blocks, 16 waves/CU
#define NB 2        // batches per thread (K reused in-register across both)

typedef float nf4 __attribute__((ext_vector_type(4)));

// Load one 12-float padded window row (cols w0-4..w0+7) as 3 float4s.
// OOB rows/cols produce zeros. gr is block-uniform (branch, not divergence).
__device__ __forceinline__ void load_row(const float* __restrict__ fb, int gr,
                                         bool wl, bool wr, int w0, nf4* d) {
    if (gr >= 0 && gr < H) {
        const float* row = fb + (size_t)gr * W;
        d[0] = wl ? *reinterpret_cast<const nf4*>(row + w0 - 4) : (nf4)0.f;
        d[1] =      *reinterpret_cast<const nf4*>(row + w0);
        d[2] = wr ? *reinterpret_cast<const nf4*>(row + w0 + 4) : (nf4)0.f;
    } else {
        d[0] = (nf4)0.f; d[1] = (nf4)0.f; d[2] = (nf4)0.f;
    }
}

// NO LDS, NO BARRIERS. 128 threads/block; thread = 4 cols x 2 batches,
// walking 4 rows with a register-rolling 5-row x 12-col f window per batch.
// K tap-rows double-buffered one i-iteration ahead; f row prefetched a full
// step ahead. Occupancy comes from the GRID (2048 blocks = 4 waves/SIMD);
// launch_bounds stays at 2 waves/EU so the allocator keeps ~108 VGPRs —
// R8's (128,4) clamp forced 64 VGPRs and spilled 700 MB to scratch.
__global__ __launch_bounds__(128, 2) void op2d_kernel(
    const float* __restrict__ f,   // (B,H,W)
    const float* __restrict__ K,   // (5,5,H,W)
    const float* __restrict__ dt,  // (B,)
    float* __restrict__ out)       // (B,H,W)
{
    const int tid  = threadIdx.x;            // 0..127
    const int w0   = tid * 4;                // 0..508
    const int hblk = blockIdx.x * NROWS;     // first output row
    const int b0   = blockIdx.y * NB;        // first batch

    const bool wl = (w0 >= 4);
    const bool wr = (w0 <= 504);

    const float* fb[NB] = { f + (size_t)b0 * HW, f + (size_t)(b0 + 1) * HW };
    const float dtb[NB] = { dt[b0], dt[b0 + 1] };

    // f window: win[b][slot][0..2], slot = (global_row - hblk + 2) mod 5.
    nf4 win[NB][5][3];

    // ---- prologue: rows hblk-2 .. hblk+2 -> slots 0..4 ----
#pragma unroll
    for (int rr = 0; rr < 5; ++rr) {
#pragma unroll
        for (int b = 0; b < NB; ++b)
            load_row(fb[b], hblk - 2 + rr, wl, wr, w0, win[b][rr]);
    }

    // K tap-row 0 of step 0 (in flight alongside the prologue f loads).
    nf4 Kv[2][KS];
#pragma unroll
    for (int j = 0; j < KS; ++j)
        Kv[0][j] = *reinterpret_cast<const nf4*>(
            K + ((size_t)j * H + hblk) * W + w0);

#pragma unroll
    for (int s = 0; s < NROWS; ++s) {
        const int r = hblk + s;              // output row this step

        // Prefetch f row r+3 (enters window slot s%5 at step end; first
        // consumed at step s+1 -> ~a full step of latency cover).
        nf4 nxt[NB][3];
#pragma unroll
        for (int b = 0; b < NB; ++b)
            load_row(fb[b], r + 3, wl, wr, w0, nxt[b]);

        float acc[NB][4] = {{0.f,0.f,0.f,0.f},{0.f,0.f,0.f,0.f}};
        float fc[NB][4];

#pragma unroll
        for (int i = 0; i < KS; ++i) {
            const int g = s * KS + i;        // global tap counter (parity)
            // Prefetch next K tap-row (same step, or row 0 of next step).
            if (i + 1 < KS) {
#pragma unroll
                for (int j = 0; j < KS; ++j)
                    Kv[(g + 1) & 1][j] = *reinterpret_cast<const nf4*>(
                        K + ((size_t)((i + 1) * KS + j) * H + r) * W + w0);
            } else if (s + 1 < NROWS) {
#pragma unroll
                for (int j = 0; j < KS; ++j)
                    Kv[(g + 1) & 1][j] = *reinterpret_cast<const nf4*>(
                        K + ((size_t)j * H + (r + 1)) * W + w0);
            }
            const nf4* Kc = Kv[g & 1];

#pragma unroll
            for (int b = 0; b < NB; ++b) {
                const int slot = (s + i) % 5;          // row r+i-2
                const nf4 ra = win[b][slot][0];
                const nf4 rb = win[b][slot][1];
                const nf4 rc = win[b][slot][2];
                const float buf[12] = { ra.x, ra.y, ra.z, ra.w,
                                        rb.x, rb.y, rb.z, rb.w,
                                        rc.x, rc.y, rc.z, rc.w };
                if (i == 2) { fc[b][0] = rb.x; fc[b][1] = rb.y;
                              fc[b][2] = rb.z; fc[b][3] = rb.w; }
#pragma unroll
                for (int j = 0; j < KS; ++j) {
                    acc[b][0] += Kc[j].x * buf[j + 2];
                    acc[b][1] += Kc[j].y * buf[j + 3];
                    acc[b][2] += Kc[j].z * buf[j + 4];
                    acc[b][3] += Kc[j].w * buf[j + 5];
                }
            }
        }

        // Store both batches' outputs for row r.
#pragma unroll
        for (int b = 0; b < NB; ++b) {
            nf4 o;
            o.x = fmaxf(fc[b][0] + acc[b][0] * dtb[b], 0.f);
            o.y = fmaxf(fc[b][1] + acc[b][1] * dtb[b], 0.f);
            o.z = fmaxf(fc[b][2] + acc[b][2] * dtb[b], 0.f);
            o.w = fmaxf(fc[b][3] + acc[b][3] * dtb[b], 0.f);
            __builtin_nontemporal_store(o,
                reinterpret_cast<nf4*>(out + ((size_t)(b0 + b) * H + r) * W + w0));
        }

        // Rotate: new bottom row (r+3) replaces departing row (r-2), slot s%5.
#pragma unroll
        for (int b = 0; b < NB; ++b) {
            win[b][s % 5][0] = nxt[b][0];
            win[b][s % 5][1] = nxt[b][1];
            win[b][s % 5][2] = nxt[b][2];
        }
    }
}

extern "C" void kernel_launch(void* const* d_in, const int* in_sizes, int n_in,
                              void* d_out, int out_size, void* d_ws, size_t ws_size,
                              hipStream_t stream) {
    const float* f  = (const float*)d_in[0];   // (32,512,512)
    const float* K  = (const float*)d_in[1];   // (5,5,512,512)
    const float* dt = (const float*)d_in[2];   // (32,)
    float* out = (float*)d_out;

    dim3 block(128);
    // x = row-group (128), y = batch-pair (16): 2048 blocks, 16 waves/CU;
    // same-K blocks are 128 IDs apart = 0 mod 8 -> same XCD.
    dim3 grid(H / NROWS, BATCH / NB);
    op2d_kernel<<<grid, block, 0, stream>>>(f, K, dt, out);
}